// Round 5
// baseline (128.124 us; speedup 1.0000x reference)
//
#include <hip/hip_runtime.h>
#include <hip/hip_bf16.h>
#include <hip/hip_fp16.h>

// SpMM: out[r] = sum_e (rows[e]==r) vals[e] * x[cols[e], :]
// rows sorted ascending (CSR-like). N=100000, E=1600000, D=48.
//
// R13: revert to measured-best R9 structure (117.9 us) + nontemporal
//   hints on the zero-reuse edge streams (cols, vals) and convert's x
//   reads, so they stop evicting the 6.4 MB xq gather table from the
//   4 MB/XCD L2. cols/vals have NO cross-wave reuse (each edge range is
//   consumed by exactly one 12-lane group in one wave) -> NT is strictly
//   pollution-removal, no locality lost.
// Model (survives R10+R12 falsifications): spmm is bound by the fabric
//   random-64B-sector floor (~3.4 TB/s) x effective L2 hit rate. Ideal
//   capacity hit = 4/6.4 = 62%; measured ~27 us implies ~45-50% because
//   streams thrash xq. NT hints recover toward the 62% ceiling.
// History:
//  - R12 scale folded into sv via E-parallel prep: NEUTRAL fill-normalized
//    (spmm -2, prep +3). Request-count theory falsified.
//  - R10 two-pass 32 B rows, TPR 6: REGRESSED 159.7 (halved threads ->
//    each pass ran ~90% of R9's whole spmm; parallelism matters).
//  - R9 int8 64 B rows single pass: BEST 117.9 us, absmax 0.125.
//  - R4/R5 pad fp16 rows to 128 B: REGRESSED. R7 fp16 split: REGRESSED.
//  - fp8 / int4 rejected on error budget (~1.0 / ~1.3 predicted absmax).

#define D_FEAT 48
#define TPR 12          // threads per row (each owns a 4-feature slice)
#define RPB 16          // rows per block
#define BLOCK (TPR * RPB)  // 192
#define ROW_BYTES 64    // int8 row: 48 q + 4 scale + 12 pad

typedef float vfloat4 __attribute__((ext_vector_type(4)));

__global__ void build_row_ptr_scatter(const int* __restrict__ rows,
                                      int* __restrict__ row_ptr,
                                      int n_edges, int n_nodes) {
    int e = blockIdx.x * blockDim.x + threadIdx.x;
    if (e >= n_edges) return;
    const int r     = rows[e];
    const int rprev = (e == 0) ? -1 : rows[e - 1];
    for (int q = rprev + 1; q <= r; ++q) row_ptr[q] = e;
    if (e == n_edges - 1) {
        for (int q = r + 1; q <= n_nodes; ++q) row_ptr[q] = n_edges;
    }
}

// Quantize x rows to int8 with per-row scale. 12 threads/row, LDS max-reduce.
__global__ __launch_bounds__(BLOCK) void convert_x_i8(
        const float* __restrict__ x,
        unsigned char* __restrict__ xq, int n_nodes) {
    __shared__ float smax[RPB][TPR];
    const int tid = threadIdx.x;
    const int fg  = tid % TPR;
    const int rib = tid / TPR;
    const int r   = blockIdx.x * RPB + rib;

    vfloat4 f = (vfloat4)(0.f);
    if (r < n_nodes)
        f = __builtin_nontemporal_load(
              reinterpret_cast<const vfloat4*>(x) + (size_t)r * TPR + fg);

    smax[rib][fg] = fmaxf(fmaxf(fabsf(f.x), fabsf(f.y)),
                          fmaxf(fabsf(f.z), fabsf(f.w)));
    __syncthreads();

    float rmax = 0.f;
#pragma unroll
    for (int i = 0; i < TPR; ++i) rmax = fmaxf(rmax, smax[rib][i]);
    if (r >= n_nodes) return;

    const float inv = (rmax > 0.f) ? (127.0f / rmax) : 0.f;

    union { signed char c[4]; unsigned int u; } pk;
    pk.c[0] = (signed char)(int)rintf(fminf(fmaxf(f.x * inv, -127.f), 127.f));
    pk.c[1] = (signed char)(int)rintf(fminf(fmaxf(f.y * inv, -127.f), 127.f));
    pk.c[2] = (signed char)(int)rintf(fminf(fmaxf(f.z * inv, -127.f), 127.f));
    pk.c[3] = (signed char)(int)rintf(fminf(fmaxf(f.w * inv, -127.f), 127.f));

    unsigned char* row = xq + (size_t)r * ROW_BYTES;
    *reinterpret_cast<unsigned int*>(row + fg * 4) = pk.u;
    if (fg == 0) *reinterpret_cast<float*>(row + 48) = rmax * (1.0f / 127.0f);
}

__device__ __forceinline__ void fma4_q(vfloat4& acc, float vs, unsigned int q) {
    acc.x += vs * (float)(int)(signed char)(q & 0xffu);
    acc.y += vs * (float)(int)(signed char)((q >> 8) & 0xffu);
    acc.z += vs * (float)(int)(signed char)((q >> 16) & 0xffu);
    acc.w += vs * (float)(int)(signed char)(q >> 24);
}

__global__ __launch_bounds__(BLOCK) void spmm_rows_i8(
        const int* __restrict__ row_ptr,
        const int* __restrict__ cols,
        const float* __restrict__ vals,
        const unsigned char* __restrict__ xq,
        float* __restrict__ out,
        int n_nodes) {
    const int tid = threadIdx.x;
    const int fg  = tid % TPR;
    const int rib = tid / TPR;
    const int r   = blockIdx.x * RPB + rib;
    if (r >= n_nodes) return;

    const int e0 = row_ptr[r];
    const int e1 = row_ptr[r + 1];

    vfloat4 acc = (vfloat4)(0.f);

    int e = e0;
    // 8-edge unroll: 16 independent gather chains (q + scale) in flight.
    // cols/vals nontemporal: zero cross-wave reuse, must not evict xq.
    for (; e + 7 < e1; e += 8) {
        int   c[8];
        float v[8];
#pragma unroll
        for (int j = 0; j < 8; ++j) {
            c[j] = __builtin_nontemporal_load(cols + e + j);
            v[j] = __builtin_nontemporal_load(vals + e + j);
        }
        unsigned int q[8];
        float        s[8];
#pragma unroll
        for (int j = 0; j < 8; ++j) {
            const unsigned char* row = xq + (size_t)c[j] * ROW_BYTES;
            q[j] = *reinterpret_cast<const unsigned int*>(row + fg * 4);
            s[j] = *reinterpret_cast<const float*>(row + 48);
        }
#pragma unroll
        for (int j = 0; j < 8; ++j) fma4_q(acc, v[j] * s[j], q[j]);
    }
    for (; e + 3 < e1; e += 4) {
        int   c[4];
        float v[4];
#pragma unroll
        for (int j = 0; j < 4; ++j) {
            c[j] = __builtin_nontemporal_load(cols + e + j);
            v[j] = __builtin_nontemporal_load(vals + e + j);
        }
        unsigned int q[4];
        float        s[4];
#pragma unroll
        for (int j = 0; j < 4; ++j) {
            const unsigned char* row = xq + (size_t)c[j] * ROW_BYTES;
            q[j] = *reinterpret_cast<const unsigned int*>(row + fg * 4);
            s[j] = *reinterpret_cast<const float*>(row + 48);
        }
#pragma unroll
        for (int j = 0; j < 4; ++j) fma4_q(acc, v[j] * s[j], q[j]);
    }
    for (; e < e1; ++e) {
        const unsigned char* row =
            xq + (size_t)__builtin_nontemporal_load(cols + e) * ROW_BYTES;
        const unsigned int  q = *reinterpret_cast<const unsigned int*>(row + fg * 4);
        const float         s = *reinterpret_cast<const float*>(row + 48);
        fma4_q(acc, __builtin_nontemporal_load(vals + e) * s, q);
    }

    __builtin_nontemporal_store(acc,
        reinterpret_cast<vfloat4*>(out + (size_t)r * D_FEAT + fg * 4));
}

// f32 fallback (used only if ws_size can't hold the quantized copy)
__global__ __launch_bounds__(BLOCK) void spmm_rows_f32(
        const int* __restrict__ row_ptr,
        const int* __restrict__ cols,
        const float* __restrict__ vals,
        const float* __restrict__ x,
        float* __restrict__ out,
        int n_nodes) {
    const int tid = threadIdx.x;
    const int fg  = tid % TPR;
    const int rib = tid / TPR;
    const int r   = blockIdx.x * RPB + rib;
    if (r >= n_nodes) return;
    const int e0 = row_ptr[r];
    const int e1 = row_ptr[r + 1];
    float4 acc = make_float4(0.f, 0.f, 0.f, 0.f);
    for (int e = e0; e < e1; ++e) {
        const float v = vals[e];
        const float4 xa = *reinterpret_cast<const float4*>(
            x + (size_t)cols[e] * D_FEAT + fg * 4);
        acc.x += v * xa.x; acc.y += v * xa.y;
        acc.z += v * xa.z; acc.w += v * xa.w;
    }
    *reinterpret_cast<float4*>(out + (size_t)r * D_FEAT + fg * 4) = acc;
}

extern "C" void kernel_launch(void* const* d_in, const int* in_sizes, int n_in,
                              void* d_out, int out_size, void* d_ws, size_t ws_size,
                              hipStream_t stream) {
    // inputs: t(f32,1), x(f32,N*48), rows(i32,E), cols(i32,E), vals(f32,E)
    const float* x    = (const float*)d_in[1];
    const int*   rows = (const int*)  d_in[2];
    const int*   cols = (const int*)  d_in[3];
    const float* vals = (const float*)d_in[4];
    float*       out  = (float*)d_out;

    const int n_edges = in_sizes[2];
    const int n_nodes = out_size / D_FEAT;     // 100000

    int* row_ptr = (int*)d_ws;                 // (n_nodes+1) ints
    const size_t rp_bytes = (size_t)(n_nodes + 1) * sizeof(int);
    const size_t xq_off   = (rp_bytes + 255) & ~(size_t)255;
    const size_t need     = xq_off + (size_t)n_nodes * ROW_BYTES;

    {
        const int threads = 256;
        const int grid = (n_edges + threads - 1) / threads;
        build_row_ptr_scatter<<<grid, threads, 0, stream>>>(rows, row_ptr, n_edges, n_nodes);
    }

    if (ws_size >= need) {
        unsigned char* xq = (unsigned char*)d_ws + xq_off;
        {
            const int grid = (n_nodes + RPB - 1) / RPB;
            convert_x_i8<<<grid, BLOCK, 0, stream>>>(x, xq, n_nodes);
        }
        const int grid = (n_nodes + RPB - 1) / RPB;
        spmm_rows_i8<<<grid, BLOCK, 0, stream>>>(row_ptr, cols, vals, xq, out, n_nodes);
    } else {
        const int grid = (n_nodes + RPB - 1) / RPB;
        spmm_rows_f32<<<grid, BLOCK, 0, stream>>>(row_ptr, cols, vals, x, out, n_nodes);
    }
}

// Round 6
// 116.670 us; speedup vs baseline: 1.0982x; 1.0982x over previous
//
#include <hip/hip_runtime.h>
#include <hip/hip_bf16.h>
#include <hip/hip_fp16.h>

// SpMM: out[r] = sum_e (rows[e]==r) vals[e] * x[cols[e], :]
// rows sorted ascending (CSR-like). N=100000, E=1600000, D=48.
//
// R14: EXACT revert to R9 (measured best, 117.9 us, absmax 0.125).
//   int8 rows: 48 q + f32 scale @48 + 12 pad = 64 B aligned -> one L2
//   sector per edge gather. Regular loads everywhere (L1 serves the
//   12-lane broadcast of cols/vals and the 8-consecutive-int reuse);
//   nontemporal on the out store only.
// Final model (survives R10/R12/R13 falsifications): spmm (~27 us) sits
//   at the random-gather fabric floor: ~1x 64 B line request/edge, ~50%
//   effective L2 hit, L3 random-sector service ~3.4 TB/s, latency fully
//   hidden by ~18k waves. Falsified levers:
//  - R10 two-pass 32 B rows (bytes/2, threads/2): REGRESSED 159.7.
//  - R12 sv=vals*scale prep (requests/2): NEUTRAL (spmm -2, prep +3).
//  - R13 nontemporal cols/vals: REGRESSED ~7 us (killed L1 reuse of the
//    12-lane broadcast + 8-consecutive-element locality).
//  - R4/R5 128 B fp16 pad: REGRESSED. R7 fp16 split+XCD pin: REGRESSED.
//  - fp8 / int4: rejected on error budget (~1.0 / ~1.3 predicted absmax
//    vs 0.3 threshold). int8+row-scale measured absmax 0.125.
// ~85 us of the total is harness-fixed (268 MB ws poison fill + input
// restores at the fill roofline); controllable remainder ~33 us is
// within ~10-15% of the structural floor above.

#define D_FEAT 48
#define TPR 12          // threads per row (each owns a 4-feature slice)
#define RPB 16          // rows per block
#define BLOCK (TPR * RPB)  // 192
#define ROW_BYTES 64    // int8 row: 48 q + 4 scale + 12 pad

typedef float vfloat4 __attribute__((ext_vector_type(4)));

__global__ void build_row_ptr_scatter(const int* __restrict__ rows,
                                      int* __restrict__ row_ptr,
                                      int n_edges, int n_nodes) {
    int e = blockIdx.x * blockDim.x + threadIdx.x;
    if (e >= n_edges) return;
    const int r     = rows[e];
    const int rprev = (e == 0) ? -1 : rows[e - 1];
    for (int q = rprev + 1; q <= r; ++q) row_ptr[q] = e;
    if (e == n_edges - 1) {
        for (int q = r + 1; q <= n_nodes; ++q) row_ptr[q] = n_edges;
    }
}

// Quantize x rows to int8 with per-row scale. 12 threads/row, LDS max-reduce.
__global__ __launch_bounds__(BLOCK) void convert_x_i8(
        const float* __restrict__ x,
        unsigned char* __restrict__ xq, int n_nodes) {
    __shared__ float smax[RPB][TPR];
    const int tid = threadIdx.x;
    const int fg  = tid % TPR;
    const int rib = tid / TPR;
    const int r   = blockIdx.x * RPB + rib;

    float4 f = make_float4(0.f, 0.f, 0.f, 0.f);
    if (r < n_nodes)
        f = reinterpret_cast<const float4*>(x)[(size_t)r * (D_FEAT / 4) + fg];

    float lmax = fmaxf(fmaxf(fabsf(f.x), fabsf(f.y)),
                       fmaxf(fabsf(f.z), fabsf(f.w)));
    smax[rib][fg] = lmax;
    __syncthreads();

    float rmax = 0.f;
#pragma unroll
    for (int i = 0; i < TPR; ++i) rmax = fmaxf(rmax, smax[rib][i]);
    if (r >= n_nodes) return;

    const float scale = rmax * (1.0f / 127.0f);
    const float inv   = (rmax > 0.f) ? (127.0f / rmax) : 0.f;

    union { signed char c[4]; unsigned int u; } pk;
    pk.c[0] = (signed char)(int)rintf(fminf(fmaxf(f.x * inv, -127.f), 127.f));
    pk.c[1] = (signed char)(int)rintf(fminf(fmaxf(f.y * inv, -127.f), 127.f));
    pk.c[2] = (signed char)(int)rintf(fminf(fmaxf(f.z * inv, -127.f), 127.f));
    pk.c[3] = (signed char)(int)rintf(fminf(fmaxf(f.w * inv, -127.f), 127.f));

    unsigned char* row = xq + (size_t)r * ROW_BYTES;
    *reinterpret_cast<unsigned int*>(row + fg * 4) = pk.u;
    if (fg == 0) *reinterpret_cast<float*>(row + 48) = scale;
}

__device__ __forceinline__ void fma4_q(vfloat4& acc, float vs, unsigned int q) {
    // compiler: v_bfe_i32 + v_cvt_f32_i32 + v_fmac_f32 per lane-feature
    acc.x += vs * (float)(int)(signed char)(q & 0xffu);
    acc.y += vs * (float)(int)(signed char)((q >> 8) & 0xffu);
    acc.z += vs * (float)(int)(signed char)((q >> 16) & 0xffu);
    acc.w += vs * (float)(int)(signed char)(q >> 24);
}

__global__ __launch_bounds__(BLOCK) void spmm_rows_i8(
        const int* __restrict__ row_ptr,
        const int* __restrict__ cols,
        const float* __restrict__ vals,
        const unsigned char* __restrict__ xq,
        float* __restrict__ out,
        int n_nodes) {
    const int tid = threadIdx.x;
    const int fg  = tid % TPR;
    const int rib = tid / TPR;
    const int r   = blockIdx.x * RPB + rib;
    if (r >= n_nodes) return;

    const int e0 = row_ptr[r];
    const int e1 = row_ptr[r + 1];

    vfloat4 acc = (vfloat4)(0.f);

    int e = e0;
    // 8-edge unroll: 16 independent gather chains (q + scale) in flight.
    // Scale shares the data's 64 B sector -> no extra sector traffic.
    for (; e + 7 < e1; e += 8) {
        int   c[8];
        float v[8];
#pragma unroll
        for (int j = 0; j < 8; ++j) { c[j] = cols[e + j]; v[j] = vals[e + j]; }
        unsigned int q[8];
        float        s[8];
#pragma unroll
        for (int j = 0; j < 8; ++j) {
            const unsigned char* row = xq + (size_t)c[j] * ROW_BYTES;
            q[j] = *reinterpret_cast<const unsigned int*>(row + fg * 4);
            s[j] = *reinterpret_cast<const float*>(row + 48);
        }
#pragma unroll
        for (int j = 0; j < 8; ++j) fma4_q(acc, v[j] * s[j], q[j]);
    }
    for (; e + 3 < e1; e += 4) {
        int   c[4];
        float v[4];
#pragma unroll
        for (int j = 0; j < 4; ++j) { c[j] = cols[e + j]; v[j] = vals[e + j]; }
        unsigned int q[4];
        float        s[4];
#pragma unroll
        for (int j = 0; j < 4; ++j) {
            const unsigned char* row = xq + (size_t)c[j] * ROW_BYTES;
            q[j] = *reinterpret_cast<const unsigned int*>(row + fg * 4);
            s[j] = *reinterpret_cast<const float*>(row + 48);
        }
#pragma unroll
        for (int j = 0; j < 4; ++j) fma4_q(acc, v[j] * s[j], q[j]);
    }
    for (; e < e1; ++e) {
        const unsigned char* row = xq + (size_t)cols[e] * ROW_BYTES;
        const unsigned int  q = *reinterpret_cast<const unsigned int*>(row + fg * 4);
        const float         s = *reinterpret_cast<const float*>(row + 48);
        fma4_q(acc, vals[e] * s, q);
    }

    __builtin_nontemporal_store(acc,
        reinterpret_cast<vfloat4*>(out + (size_t)r * D_FEAT + fg * 4));
}

// f32 fallback (used only if ws_size can't hold the quantized copy)
__global__ __launch_bounds__(BLOCK) void spmm_rows_f32(
        const int* __restrict__ row_ptr,
        const int* __restrict__ cols,
        const float* __restrict__ vals,
        const float* __restrict__ x,
        float* __restrict__ out,
        int n_nodes) {
    const int tid = threadIdx.x;
    const int fg  = tid % TPR;
    const int rib = tid / TPR;
    const int r   = blockIdx.x * RPB + rib;
    if (r >= n_nodes) return;
    const int e0 = row_ptr[r];
    const int e1 = row_ptr[r + 1];
    float4 acc = make_float4(0.f, 0.f, 0.f, 0.f);
    for (int e = e0; e < e1; ++e) {
        const float v = vals[e];
        const float4 xa = *reinterpret_cast<const float4*>(
            x + (size_t)cols[e] * D_FEAT + fg * 4);
        acc.x += v * xa.x; acc.y += v * xa.y;
        acc.z += v * xa.z; acc.w += v * xa.w;
    }
    *reinterpret_cast<float4*>(out + (size_t)r * D_FEAT + fg * 4) = acc;
}

extern "C" void kernel_launch(void* const* d_in, const int* in_sizes, int n_in,
                              void* d_out, int out_size, void* d_ws, size_t ws_size,
                              hipStream_t stream) {
    // inputs: t(f32,1), x(f32,N*48), rows(i32,E), cols(i32,E), vals(f32,E)
    const float* x    = (const float*)d_in[1];
    const int*   rows = (const int*)  d_in[2];
    const int*   cols = (const int*)  d_in[3];
    const float* vals = (const float*)d_in[4];
    float*       out  = (float*)d_out;

    const int n_edges = in_sizes[2];
    const int n_nodes = out_size / D_FEAT;     // 100000

    int* row_ptr = (int*)d_ws;                 // (n_nodes+1) ints
    const size_t rp_bytes = (size_t)(n_nodes + 1) * sizeof(int);
    const size_t xq_off   = (rp_bytes + 255) & ~(size_t)255;
    const size_t need     = xq_off + (size_t)n_nodes * ROW_BYTES;

    {
        const int threads = 256;
        const int grid = (n_edges + threads - 1) / threads;
        build_row_ptr_scatter<<<grid, threads, 0, stream>>>(rows, row_ptr, n_edges, n_nodes);
    }

    if (ws_size >= need) {
        unsigned char* xq = (unsigned char*)d_ws + xq_off;
        {
            const int grid = (n_nodes + RPB - 1) / RPB;
            convert_x_i8<<<grid, BLOCK, 0, stream>>>(x, xq, n_nodes);
        }
        const int grid = (n_nodes + RPB - 1) / RPB;
        spmm_rows_i8<<<grid, BLOCK, 0, stream>>>(row_ptr, cols, vals, xq, out, n_nodes);
    } else {
        const int grid = (n_nodes + RPB - 1) / RPB;
        spmm_rows_f32<<<grid, BLOCK, 0, stream>>>(row_ptr, cols, vals, x, out, n_nodes);
    }
}